// Round 4
// baseline (2932.535 us; speedup 1.0000x reference)
//
#include <hip/hip_runtime.h>
#include <hip/hip_bf16.h>

#define T_LEN 256
#define B_DIM 128
#define I_DIM 256
#define H_DIM 1024
#define BH (B_DIM * H_DIM)          // 131072

typedef __attribute__((ext_vector_type(8))) short short8;
typedef __attribute__((ext_vector_type(4))) float f32x4;

static __device__ __forceinline__ unsigned short f2bf(float f) {
  unsigned u = __float_as_uint(f);
  return (unsigned short)((u + 0x7fffu + ((u >> 16) & 1u)) >> 16);
}

// ---------------------------------------------------------------------------
// Phase 1: x_proj GEMM (fp32, unchanged).
// ---------------------------------------------------------------------------
__global__ __launch_bounds__(256) void xproj_gemm(
    const float* __restrict__ A, const float* __restrict__ W,
    const float* __restrict__ bias, float* __restrict__ C) {
  __shared__ float As[64][33];
  __shared__ float Ws[64][33];

  const int tid = threadIdx.x;
  const int m0 = blockIdx.y * 64;
  const int n0 = blockIdx.x * 64;
  const int ty = tid >> 4;
  const int tx = tid & 15;
  const int r   = tid >> 3;
  const int c4  = (tid & 7) << 2;

  float acc[4][4] = {};

  for (int kc = 0; kc < I_DIM; kc += 32) {
#pragma unroll
    for (int p = 0; p < 2; ++p) {
      const int rr = r + p * 32;
      const float4 a = *(const float4*)(A + (size_t)(m0 + rr) * I_DIM + kc + c4);
      As[rr][c4 + 0] = a.x; As[rr][c4 + 1] = a.y;
      As[rr][c4 + 2] = a.z; As[rr][c4 + 3] = a.w;
      const float4 w = *(const float4*)(W + (size_t)(n0 + rr) * I_DIM + kc + c4);
      Ws[rr][c4 + 0] = w.x; Ws[rr][c4 + 1] = w.y;
      Ws[rr][c4 + 2] = w.z; Ws[rr][c4 + 3] = w.w;
    }
    __syncthreads();
#pragma unroll
    for (int k = 0; k < 32; ++k) {
      float av[4], wv[4];
#pragma unroll
      for (int i = 0; i < 4; ++i) av[i] = As[ty * 4 + i][k];
#pragma unroll
      for (int j = 0; j < 4; ++j) wv[j] = Ws[tx * 4 + j][k];
#pragma unroll
      for (int i = 0; i < 4; ++i)
#pragma unroll
        for (int j = 0; j < 4; ++j)
          acc[i][j] = fmaf(av[i], wv[j], acc[i][j]);
    }
    __syncthreads();
  }

  const float4 bv = *(const float4*)(bias + n0 + tx * 4);
#pragma unroll
  for (int i = 0; i < 4; ++i) {
    float4 o;
    o.x = acc[i][0] + bv.x;
    o.y = acc[i][1] + bv.y;
    o.z = acc[i][2] + bv.z;
    o.w = acc[i][3] + bv.w;
    *(float4*)(C + (size_t)(m0 + ty * 4 + i) * H_DIM + n0 + tx * 4) = o;
  }
}

__global__ __launch_bounds__(256) void init_hT0(
    const float* __restrict__ h0, unsigned short* __restrict__ hT) {
  const int idx = blockIdx.x * 256 + threadIdx.x;    // [0, 131072)
  hT[idx] = f2bf(h0[idx & (H_DIM - 1)]);
}

// ---------------------------------------------------------------------------
// Phase 2: ONE persistent kernel runs all 256 steps.
// Grid 256 = 8 b-groups (bg = bid&7; bid%8 tracks XCD) x 32 j-slots.
// Block: 16 b x 32 j. W_hh slice (32x1024) converted bf16 -> LDS once.
// 4 waves = (jh in 2) x (kh in 2); 16 MFMA(16x16x32_bf16)/wave/step.
// fp32 master state lives in epilogue-thread registers (exact leak term).
// Per-bg barrier: arrive[32] flags + leader release, agent-scope fences.
// Flags compared with == so the 0xAA ws poison needs no initialization.
// ---------------------------------------------------------------------------
#define WPAD 1032                    // LDS row stride (shorts): +8 pad -> 2-way max

__global__ __launch_bounds__(256) void rnn_persist(
    const float* __restrict__ W_hh,
    const float* __restrict__ b_hh,
    const float* __restrict__ h0,
    unsigned short* __restrict__ hT,   // ping-pong: 2 x BH bf16
    int* __restrict__ arrive,          // [8][32]
    int* __restrict__ release,         // [8] stride 32 ints
    float* __restrict__ out)           // [T][B][H]
{
  __shared__ unsigned short Wlds[32 * WPAD];
  __shared__ float red[2][16][17];

  const int tid  = threadIdx.x;
  const int bg    = blockIdx.x & 7;
  const int jslot = blockIdx.x >> 3;
  const int wv   = tid >> 6;
  const int lane = tid & 63;
  const int ln   = lane & 15;
  const int q    = lane >> 4;

  const int jh = wv & 1;
  const int kh = wv >> 1;
  const int j0 = jslot * 32;
  const int b0 = bg * 16;

  // ---- stage W slice -> bf16 LDS (once) ----
  {
    const int jl = tid >> 3;                 // 0..31
    const int kb = (tid & 7) * 128;
    const float* src = W_hh + (size_t)(j0 + jl) * H_DIM + kb;
    unsigned short* dst = &Wlds[jl * WPAD + kb];
#pragma unroll
    for (int i = 0; i < 128; i += 4) {
      const float4 w = *(const float4*)(src + i);
      ushort4 o;
      o.x = f2bf(w.x); o.y = f2bf(w.y); o.z = f2bf(w.z); o.w = f2bf(w.w);
      *(ushort4*)(dst + i) = o;
    }
  }
  __syncthreads();

  // per-thread constants
  const int jg = j0 + jh * 16 + ln;          // epilogue j (kh==0 waves)
  const float bj = b_hh[jg];
  float hstate[4];
  {
    const float h0v = h0[jg];
#pragma unroll
    for (int r = 0; r < 4; ++r) hstate[r] = h0v;
  }

  const int wrow = (jh * 16 + ln) * WPAD + kh * 512 + q * 8;

  for (int t = 0; t < T_LEN; ++t) {
    const unsigned short* hcur = hT + (size_t)(t & 1) * BH;
    unsigned short* hnxt       = hT + (size_t)((t + 1) & 1) * BH;
    float* outT = out + (size_t)t * BH;

    // prefetch xp (independent of barrier/h)
    float xp[4];
    if (kh == 0) {
#pragma unroll
      for (int r = 0; r < 4; ++r)
        xp[r] = outT[(size_t)(b0 + q * 4 + r) * H_DIM + jg];
    }

    // ---- MFMA: 16 chunks of K=32 over this wave's k-half ----
    const unsigned short* hrow =
        hcur + (size_t)(b0 + ln) * H_DIM + kh * 512 + q * 8;
    short8 a[16];
#pragma unroll
    for (int c = 0; c < 16; ++c) a[c] = *(const short8*)(hrow + c * 32);

    f32x4 acc = {0.f, 0.f, 0.f, 0.f};
#pragma unroll
    for (int c = 0; c < 16; ++c) {
      const short8 b = *(const short8*)(&Wlds[wrow + c * 32]);
      acc = __builtin_amdgcn_mfma_f32_16x16x32_bf16(a[c], b, acc, 0, 0, 0);
    }

    if (kh == 1) {
#pragma unroll
      for (int r = 0; r < 4; ++r) red[jh][q * 4 + r][ln] = acc[r];
    }
    __syncthreads();

    // ---- epilogue (kh==0 waves) ----
    if (kh == 0) {
#pragma unroll
      for (int r = 0; r < 4; ++r) {
        const float rec = acc[r] + red[jh][q * 4 + r][ln];
        float v = 0.9f * hstate[r] + 0.1f * (rec + bj + xp[r]);
        v = fmaxf(v, 0.f);
        hstate[r] = v;
        const size_t oidx = (size_t)(b0 + q * 4 + r) * H_DIM + jg;
        outT[oidx] = v;
        hnxt[oidx] = f2bf(v);
      }
    }
    __syncthreads();   // all stores issued + red free for reuse

    // ---- per-bg barrier ----
    if (tid == 0) {
      __builtin_amdgcn_fence(__ATOMIC_RELEASE, "agent");   // wbl2: block's stores -> LLC
      __hip_atomic_store(&arrive[bg * 32 + jslot], t + 1,
                         __ATOMIC_RELAXED, __HIP_MEMORY_SCOPE_AGENT);
    }
    if (jslot == 0 && wv == 0 && lane < 32) {
      while (__hip_atomic_load(&arrive[bg * 32 + lane],
                               __ATOMIC_RELAXED, __HIP_MEMORY_SCOPE_AGENT) != t + 1) {}
    }
    if (jslot == 0 && tid == 0) {
      __hip_atomic_store(&release[bg * 32], t + 1,
                         __ATOMIC_RELEASE, __HIP_MEMORY_SCOPE_AGENT);
    }
    if (tid == 0) {
      while (__hip_atomic_load(&release[bg * 32],
                               __ATOMIC_RELAXED, __HIP_MEMORY_SCOPE_AGENT) != t + 1) {}
      __builtin_amdgcn_fence(__ATOMIC_ACQUIRE, "agent");   // inv: see peers' h
    }
    __syncthreads();
  }
}

// ---------------------------------------------------------------------------
extern "C" void kernel_launch(void* const* d_in, const int* in_sizes, int n_in,
                              void* d_out, int out_size, void* d_ws, size_t ws_size,
                              hipStream_t stream) {
  const float* input = (const float*)d_in[0];
  const float* W_in  = (const float*)d_in[1];
  const float* b_in  = (const float*)d_in[2];
  const float* W_hh  = (const float*)d_in[3];
  const float* b_hh  = (const float*)d_in[4];
  const float* h0    = (const float*)d_in[5];
  float* out = (float*)d_out;

  // ws: [0, 512KB) hT ping-pong bf16; then arrive[256] ints; release[256] ints.
  unsigned short* hT = (unsigned short*)d_ws;
  int* arrive  = (int*)((char*)d_ws + 2 * BH * sizeof(unsigned short));
  int* release = arrive + 256;

  init_hT0<<<BH / 256, 256, 0, stream>>>(h0, hT);

  dim3 g1(H_DIM / 64, (T_LEN * B_DIM) / 64);
  xproj_gemm<<<g1, 256, 0, stream>>>(input, W_in, b_in, out);

  rnn_persist<<<256, 256, 0, stream>>>(W_hh, b_hh, h0, hT, arrive, release, out);
}